// Round 1
// baseline (531.482 us; speedup 1.0000x reference)
//
#include <hip/hip_runtime.h>

typedef __bf16 bf16;
typedef __bf16 bf16x4 __attribute__((ext_vector_type(4)));
typedef __bf16 bf16x8 __attribute__((ext_vector_type(8)));
typedef float f32x4 __attribute__((ext_vector_type(4)));

#define NB 2
#define SEQ 4096
#define HID 768
#define NHEAD 12
#define HDIM 64
#define MTOT (NB * SEQ)   // 8192

// ---------------- fp32 -> bf16 convert (vectorized) ----------------
__global__ __launch_bounds__(256) void cvt_kernel(const float* __restrict__ in,
                                                  bf16* __restrict__ out, int n4) {
    int stride = gridDim.x * blockDim.x;
    for (int i = blockIdx.x * blockDim.x + threadIdx.x; i < n4; i += stride) {
        float4 v = reinterpret_cast<const float4*>(in)[i];
        bf16x4 o;
        o[0] = (bf16)v.x; o[1] = (bf16)v.y; o[2] = (bf16)v.z; o[3] = (bf16)v.w;
        reinterpret_cast<bf16x4*>(out)[i] = o;
    }
}

// ---------------- fused QKV projection GEMM ----------------
// C[m][n] = sum_k X[m][k] * W[n][k] + bias[n]
// grid: (6, 64, 3) blocks of 256 threads; block tile 128x128, wave tile 64x64.
__global__ __launch_bounds__(256) void qkv_gemm(
    const bf16* __restrict__ Xb,
    const bf16* __restrict__ Wq, const bf16* __restrict__ Wk, const bf16* __restrict__ Wv,
    const float* __restrict__ bq, const float* __restrict__ bk, const float* __restrict__ bv,
    bf16* __restrict__ Qh, bf16* __restrict__ Kh, bf16* __restrict__ Vt)
{
    int z = blockIdx.z;
    const bf16* W = (z == 0) ? Wq : (z == 1) ? Wk : Wv;
    const float* bias = (z == 0) ? bq : (z == 1) ? bk : bv;

    int lane = threadIdx.x & 63;
    int wid  = threadIdx.x >> 6;
    int wm = wid >> 1, wn = wid & 1;
    int g = lane >> 4, c = lane & 15;
    int m0 = blockIdx.y * 128 + wm * 64;
    int n0 = blockIdx.x * 128 + wn * 64;

    f32x4 acc[4][4] = {};
    const bf16* Aptr = Xb + (size_t)(m0 + c) * HID + g * 8;
    const bf16* Bptr = W  + (size_t)(n0 + c) * HID + g * 8;

    for (int k0 = 0; k0 < HID; k0 += 32) {
        bf16x8 a[4], b[4];
#pragma unroll
        for (int i = 0; i < 4; i++) {
            a[i] = *reinterpret_cast<const bf16x8*>(Aptr + (size_t)i * 16 * HID + k0);
            b[i] = *reinterpret_cast<const bf16x8*>(Bptr + (size_t)i * 16 * HID + k0);
        }
#pragma unroll
        for (int mi = 0; mi < 4; mi++)
#pragma unroll
            for (int ni = 0; ni < 4; ni++)
                acc[mi][ni] = __builtin_amdgcn_mfma_f32_16x16x32_bf16(a[mi], b[ni], acc[mi][ni], 0, 0, 0);
    }

#pragma unroll
    for (int ni = 0; ni < 4; ni++) {
        int n = n0 + ni * 16 + c;
        float bval = bias[n];
        int h = n >> 6, d = n & 63;
#pragma unroll
        for (int mi = 0; mi < 4; mi++) {
#pragma unroll
            for (int j = 0; j < 4; j++) {
                int m = m0 + mi * 16 + g * 4 + j;
                float val = acc[mi][ni][j] + bval;
                int bb = m >> 12, s = m & 4095;
                if (z < 2) {
                    bf16* out = (z == 0) ? Qh : Kh;
                    out[((size_t)(bb * NHEAD + h) * SEQ + s) * HDIM + d] = (bf16)val;
                } else {
                    Vt[((size_t)(bb * NHEAD + h) * HDIM + d) * SEQ + s] = (bf16)val;
                }
            }
        }
    }
}

// ---------------- flash attention ----------------
// grid: (SEQ/64, NB*NHEAD); 256 threads = 4 waves; each wave owns 16 q-rows.
__global__ __launch_bounds__(256) void attn_kernel(
    const bf16* __restrict__ Qh, const bf16* __restrict__ Kh, const bf16* __restrict__ Vt,
    const float* __restrict__ mask, bf16* __restrict__ ctx)
{
    __shared__ bf16 Kl[64][72];
    __shared__ bf16 Vl[64][72];
    __shared__ bf16 Pl[4][16][72];

    int bh = blockIdx.y;
    int b = bh / NHEAD, h = bh % NHEAD;
    int q0 = blockIdx.x * 64;
    int t = threadIdx.x;
    int lane = t & 63, w = t >> 6, g = lane >> 4, c = lane & 15;
    size_t base = (size_t)bh * SEQ * HDIM;

    int qrow = q0 + w * 16 + c;
    bf16x8 aq[2];
    aq[0] = *reinterpret_cast<const bf16x8*>(Qh + base + (size_t)qrow * HDIM + g * 8);
    aq[1] = *reinterpret_cast<const bf16x8*>(Qh + base + (size_t)qrow * HDIM + 32 + g * 8);

    float m_r[4], l_r[4];
    f32x4 o_acc[4] = {};
#pragma unroll
    for (int j = 0; j < 4; j++) { m_r[j] = -1e30f; l_r[j] = 0.f; }

    const float* maskb = mask + b * SEQ;

    for (int kt = 0; kt < SEQ / 64; kt++) {
        __syncthreads();
#pragma unroll
        for (int i = 0; i < 2; i++) {
            int chunk = t + i * 256;         // 0..511
            int row = chunk >> 3;            // 0..63
            int colo = (chunk & 7) * 8;      // 0..56
            *reinterpret_cast<bf16x8*>(&Kl[row][colo]) =
                *reinterpret_cast<const bf16x8*>(Kh + base + (size_t)(kt * 64 + row) * HDIM + colo);
            *reinterpret_cast<bf16x8*>(&Vl[row][colo]) =
                *reinterpret_cast<const bf16x8*>(Vt + base + (size_t)row * SEQ + kt * 64 + colo);
        }
        __syncthreads();

        // scores: Q(16xq,64d) x K^T -> 16x64
        f32x4 sc[4] = {};
#pragma unroll
        for (int nf = 0; nf < 4; nf++) {
#pragma unroll
            for (int ks = 0; ks < 2; ks++) {
                bf16x8 bk_ = *reinterpret_cast<const bf16x8*>(&Kl[nf * 16 + c][ks * 32 + g * 8]);
                sc[nf] = __builtin_amdgcn_mfma_f32_16x16x32_bf16(aq[ks], bk_, sc[nf], 0, 0, 0);
            }
        }

        float p[4][4];
        float mt[4];
#pragma unroll
        for (int j = 0; j < 4; j++) mt[j] = -1e30f;
#pragma unroll
        for (int nf = 0; nf < 4; nf++) {
            float mk = maskb[kt * 64 + nf * 16 + c];
#pragma unroll
            for (int j = 0; j < 4; j++) {
                float sv = sc[nf][j] * 0.125f + mk;
                p[nf][j] = sv;
                mt[j] = fmaxf(mt[j], sv);
            }
        }
#pragma unroll
        for (int j = 0; j < 4; j++) {
#pragma unroll
            for (int msk = 1; msk < 16; msk <<= 1)
                mt[j] = fmaxf(mt[j], __shfl_xor(mt[j], msk, 64));
        }
        float alpha[4];
#pragma unroll
        for (int j = 0; j < 4; j++) {
            float mnew = fmaxf(m_r[j], mt[j]);
            alpha[j] = __expf(m_r[j] - mnew);
            m_r[j] = mnew;
        }
        float rs[4];
#pragma unroll
        for (int j = 0; j < 4; j++) rs[j] = 0.f;
#pragma unroll
        for (int nf = 0; nf < 4; nf++)
#pragma unroll
            for (int j = 0; j < 4; j++) {
                p[nf][j] = __expf(p[nf][j] - m_r[j]);
                rs[j] += p[nf][j];
            }
#pragma unroll
        for (int j = 0; j < 4; j++) {
#pragma unroll
            for (int msk = 1; msk < 16; msk <<= 1)
                rs[j] += __shfl_xor(rs[j], msk, 64);
            l_r[j] = l_r[j] * alpha[j] + rs[j];
        }
#pragma unroll
        for (int nf = 0; nf < 4; nf++)
#pragma unroll
            for (int j = 0; j < 4; j++)
                o_acc[nf][j] *= alpha[j];

        // P (D-layout) -> LDS -> A-fragment layout
#pragma unroll
        for (int nf = 0; nf < 4; nf++)
#pragma unroll
            for (int j = 0; j < 4; j++)
                Pl[w][g * 4 + j][nf * 16 + c] = (bf16)p[nf][j];

        bf16x8 pa[2];
        pa[0] = *reinterpret_cast<const bf16x8*>(&Pl[w][c][g * 8]);
        pa[1] = *reinterpret_cast<const bf16x8*>(&Pl[w][c][32 + g * 8]);
#pragma unroll
        for (int nf = 0; nf < 4; nf++) {
#pragma unroll
            for (int ks = 0; ks < 2; ks++) {
                bf16x8 bv_ = *reinterpret_cast<const bf16x8*>(&Vl[nf * 16 + c][ks * 32 + g * 8]);
                o_acc[nf] = __builtin_amdgcn_mfma_f32_16x16x32_bf16(pa[ks], bv_, o_acc[nf], 0, 0, 0);
            }
        }
    }

    float inv[4];
#pragma unroll
    for (int j = 0; j < 4; j++) inv[j] = 1.f / l_r[j];
#pragma unroll
    for (int nf = 0; nf < 4; nf++) {
#pragma unroll
        for (int j = 0; j < 4; j++) {
            int srow = q0 + w * 16 + g * 4 + j;
            int d = nf * 16 + c;
            ctx[((size_t)(b * SEQ + srow)) * HID + h * HDIM + d] = (bf16)(o_acc[nf][j] * inv[j]);
        }
    }
}

// ---------------- output projection + bias + residual ----------------
__global__ __launch_bounds__(256) void oproj_gemm(
    const bf16* __restrict__ Cb, const bf16* __restrict__ Wo, const float* __restrict__ bo,
    const float* __restrict__ hidden, float* __restrict__ y)
{
    int lane = threadIdx.x & 63;
    int wid  = threadIdx.x >> 6;
    int wm = wid >> 1, wn = wid & 1;
    int g = lane >> 4, c = lane & 15;
    int m0 = blockIdx.y * 128 + wm * 64;
    int n0 = blockIdx.x * 128 + wn * 64;

    f32x4 acc[4][4] = {};
    const bf16* Aptr = Cb + (size_t)(m0 + c) * HID + g * 8;
    const bf16* Bptr = Wo + (size_t)(n0 + c) * HID + g * 8;

    for (int k0 = 0; k0 < HID; k0 += 32) {
        bf16x8 a[4], b[4];
#pragma unroll
        for (int i = 0; i < 4; i++) {
            a[i] = *reinterpret_cast<const bf16x8*>(Aptr + (size_t)i * 16 * HID + k0);
            b[i] = *reinterpret_cast<const bf16x8*>(Bptr + (size_t)i * 16 * HID + k0);
        }
#pragma unroll
        for (int mi = 0; mi < 4; mi++)
#pragma unroll
            for (int ni = 0; ni < 4; ni++)
                acc[mi][ni] = __builtin_amdgcn_mfma_f32_16x16x32_bf16(a[mi], b[ni], acc[mi][ni], 0, 0, 0);
    }

#pragma unroll
    for (int ni = 0; ni < 4; ni++) {
        int n = n0 + ni * 16 + c;
        float bval = bo[n];
#pragma unroll
        for (int mi = 0; mi < 4; mi++) {
#pragma unroll
            for (int j = 0; j < 4; j++) {
                int m = m0 + mi * 16 + g * 4 + j;
                size_t idx = (size_t)m * HID + n;
                y[idx] = acc[mi][ni][j] + bval + hidden[idx];
            }
        }
    }
}

// ---------------- LayerNorm ----------------
// one wave per row; 768 floats = 12 per lane (3x float4)
__global__ __launch_bounds__(256) void ln_kernel(
    const float* __restrict__ y, const float* __restrict__ gam,
    const float* __restrict__ bet, float* __restrict__ out)
{
    int row = blockIdx.x * 4 + (threadIdx.x >> 6);
    int lane = threadIdx.x & 63;
    const float* yr = y + (size_t)row * HID;

    float4 v[3];
#pragma unroll
    for (int i = 0; i < 3; i++)
        v[i] = reinterpret_cast<const float4*>(yr)[lane + i * 64];

    float s = 0.f;
#pragma unroll
    for (int i = 0; i < 3; i++) s += v[i].x + v[i].y + v[i].z + v[i].w;
#pragma unroll
    for (int msk = 1; msk < 64; msk <<= 1) s += __shfl_xor(s, msk, 64);
    float mean = s * (1.f / 768.f);

    float q = 0.f;
#pragma unroll
    for (int i = 0; i < 3; i++) {
        float dx = v[i].x - mean, dy = v[i].y - mean, dz = v[i].z - mean, dw = v[i].w - mean;
        q += dx * dx + dy * dy + dz * dz + dw * dw;
    }
#pragma unroll
    for (int msk = 1; msk < 64; msk <<= 1) q += __shfl_xor(q, msk, 64);
    float rstd = rsqrtf(q * (1.f / 768.f) + 1e-12f);

    float* outr = out + (size_t)row * HID;
#pragma unroll
    for (int i = 0; i < 3; i++) {
        float4 gg = reinterpret_cast<const float4*>(gam)[lane + i * 64];
        float4 bb = reinterpret_cast<const float4*>(bet)[lane + i * 64];
        float4 o;
        o.x = (v[i].x - mean) * rstd * gg.x + bb.x;
        o.y = (v[i].y - mean) * rstd * gg.y + bb.y;
        o.z = (v[i].z - mean) * rstd * gg.z + bb.z;
        o.w = (v[i].w - mean) * rstd * gg.w + bb.w;
        reinterpret_cast<float4*>(outr)[lane + i * 64] = o;
    }
}

extern "C" void kernel_launch(void* const* d_in, const int* in_sizes, int n_in,
                              void* d_out, int out_size, void* d_ws, size_t ws_size,
                              hipStream_t stream) {
    const float* hidden = (const float*)d_in[0];
    const float* mask   = (const float*)d_in[1];
    const float* q_w = (const float*)d_in[2];
    const float* q_b = (const float*)d_in[3];
    const float* k_w = (const float*)d_in[4];
    const float* k_b = (const float*)d_in[5];
    const float* v_w = (const float*)d_in[6];
    const float* v_b = (const float*)d_in[7];
    const float* o_w = (const float*)d_in[8];
    const float* o_b = (const float*)d_in[9];
    const float* ln_g = (const float*)d_in[10];
    const float* ln_b = (const float*)d_in[11];
    float* out = (float*)d_out;

    const size_t SZ_X = (size_t)MTOT * HID;      // 6291456
    const size_t SZ_W = (size_t)HID * HID;       // 589824

    char* ws = (char*)d_ws;
    size_t XB_OFF = 0;                            // bf16 X (also ctx after attn)
    size_t W_OFF  = XB_OFF + SZ_X * 2;            // 4 weight matrices bf16
    size_t QH_OFF = W_OFF + 4 * SZ_W * 2;         // Q head-major (y fp32 aliases QH+KH)
    size_t KH_OFF = QH_OFF + SZ_X * 2;
    size_t VT_OFF = KH_OFF + SZ_X * 2;

    bf16* Xb  = (bf16*)(ws + XB_OFF);
    bf16* Wqb = (bf16*)(ws + W_OFF);
    bf16* Wkb = Wqb + SZ_W;
    bf16* Wvb = Wkb + SZ_W;
    bf16* Wob = Wvb + SZ_W;
    bf16* Qh  = (bf16*)(ws + QH_OFF);
    bf16* Kh  = (bf16*)(ws + KH_OFF);
    bf16* Vt  = (bf16*)(ws + VT_OFF);
    bf16* ctx = (bf16*)(ws + XB_OFF);             // alias: X dead after QKV GEMM
    float* y  = (float*)(ws + QH_OFF);            // alias: Q/K dead after attention

    // converts
    cvt_kernel<<<dim3((SZ_X / 4 + 255) / 256), 256, 0, stream>>>(hidden, Xb, SZ_X / 4);
    cvt_kernel<<<dim3((SZ_W / 4 + 255) / 256), 256, 0, stream>>>(q_w, Wqb, SZ_W / 4);
    cvt_kernel<<<dim3((SZ_W / 4 + 255) / 256), 256, 0, stream>>>(k_w, Wkb, SZ_W / 4);
    cvt_kernel<<<dim3((SZ_W / 4 + 255) / 256), 256, 0, stream>>>(v_w, Wvb, SZ_W / 4);
    cvt_kernel<<<dim3((SZ_W / 4 + 255) / 256), 256, 0, stream>>>(o_w, Wob, SZ_W / 4);

    // QKV projections
    qkv_gemm<<<dim3(HID / 128, MTOT / 128, 3), 256, 0, stream>>>(
        Xb, Wqb, Wkb, Wvb, q_b, k_b, v_b, Qh, Kh, Vt);

    // attention
    attn_kernel<<<dim3(SEQ / 64, NB * NHEAD), 256, 0, stream>>>(Qh, Kh, Vt, mask, ctx);

    // output projection + residual
    oproj_gemm<<<dim3(HID / 128, MTOT / 128), 256, 0, stream>>>(ctx, Wob, o_b, hidden, y);

    // layernorm
    ln_kernel<<<dim3(MTOT / 4), 256, 0, stream>>>(y, ln_g, ln_b, out);
}

// Round 2
// 460.804 us; speedup vs baseline: 1.1534x; 1.1534x over previous
//
#include <hip/hip_runtime.h>

typedef __bf16 bf16;
typedef __bf16 bf16x4 __attribute__((ext_vector_type(4)));
typedef __bf16 bf16x8 __attribute__((ext_vector_type(8)));
typedef float f32x4 __attribute__((ext_vector_type(4)));
typedef float f32x16 __attribute__((ext_vector_type(16)));

#define NB 2
#define SEQ 4096
#define HID 768
#define NHEAD 12
#define HDIM 64
#define MTOT (NB * SEQ)   // 8192
#define LOG2E 1.4426950408889634f

__device__ inline unsigned pkbf(float a, float b) {
    union { bf16 h[2]; unsigned u; } x;
    x.h[0] = (bf16)a; x.h[1] = (bf16)b;
    return x.u;
}

// ---------------- fp32 -> bf16 convert (vectorized) ----------------
__global__ __launch_bounds__(256) void cvt_kernel(const float* __restrict__ in,
                                                  bf16* __restrict__ out, int n4) {
    int stride = gridDim.x * blockDim.x;
    for (int i = blockIdx.x * blockDim.x + threadIdx.x; i < n4; i += stride) {
        float4 v = reinterpret_cast<const float4*>(in)[i];
        bf16x4 o;
        o[0] = (bf16)v.x; o[1] = (bf16)v.y; o[2] = (bf16)v.z; o[3] = (bf16)v.w;
        reinterpret_cast<bf16x4*>(out)[i] = o;
    }
}

// ---------------- fused QKV projection GEMM ----------------
__global__ __launch_bounds__(256) void qkv_gemm(
    const bf16* __restrict__ Xb,
    const bf16* __restrict__ Wq, const bf16* __restrict__ Wk, const bf16* __restrict__ Wv,
    const float* __restrict__ bq, const float* __restrict__ bk, const float* __restrict__ bv,
    bf16* __restrict__ Qh, bf16* __restrict__ Kh, bf16* __restrict__ Vt)
{
    int z = blockIdx.z;
    const bf16* W = (z == 0) ? Wq : (z == 1) ? Wk : Wv;
    const float* bias = (z == 0) ? bq : (z == 1) ? bk : bv;

    int lane = threadIdx.x & 63;
    int wid  = threadIdx.x >> 6;
    int wm = wid >> 1, wn = wid & 1;
    int g = lane >> 4, c = lane & 15;
    int m0 = blockIdx.y * 128 + wm * 64;
    int n0 = blockIdx.x * 128 + wn * 64;

    f32x4 acc[4][4] = {};
    const bf16* Aptr = Xb + (size_t)(m0 + c) * HID + g * 8;
    const bf16* Bptr = W  + (size_t)(n0 + c) * HID + g * 8;

    for (int k0 = 0; k0 < HID; k0 += 32) {
        bf16x8 a[4], b[4];
#pragma unroll
        for (int i = 0; i < 4; i++) {
            a[i] = *reinterpret_cast<const bf16x8*>(Aptr + (size_t)i * 16 * HID + k0);
            b[i] = *reinterpret_cast<const bf16x8*>(Bptr + (size_t)i * 16 * HID + k0);
        }
#pragma unroll
        for (int mi = 0; mi < 4; mi++)
#pragma unroll
            for (int ni = 0; ni < 4; ni++)
                acc[mi][ni] = __builtin_amdgcn_mfma_f32_16x16x32_bf16(a[mi], b[ni], acc[mi][ni], 0, 0, 0);
    }

#pragma unroll
    for (int ni = 0; ni < 4; ni++) {
        int n = n0 + ni * 16 + c;
        float bval = bias[n];
        int h = n >> 6, d = n & 63;
#pragma unroll
        for (int mi = 0; mi < 4; mi++) {
#pragma unroll
            for (int j = 0; j < 4; j++) {
                int m = m0 + mi * 16 + g * 4 + j;
                float val = acc[mi][ni][j] + bval;
                int bb = m >> 12, s = m & 4095;
                if (z == 0) {
                    // pre-scale Q by 1/sqrt(HD) * log2(e) for exp2-domain softmax
                    val *= 0.125f * LOG2E;
                    Qh[((size_t)(bb * NHEAD + h) * SEQ + s) * HDIM + d] = (bf16)val;
                } else if (z == 1) {
                    Kh[((size_t)(bb * NHEAD + h) * SEQ + s) * HDIM + d] = (bf16)val;
                } else {
                    Vt[((size_t)(bb * NHEAD + h) * HDIM + d) * SEQ + s] = (bf16)val;
                }
            }
        }
    }
}

// ---------------- flash attention (swapped-QK^T, 32x32 MFMA) ----------------
// grid: (SEQ/128, NB*NHEAD); 256 threads = 4 waves; each wave owns 32 q-rows.
// Scores computed as S = K*Q^T  -> D[k][q], col = q = lane&31 (softmax per-lane).
// PV computed as O^T = V^T*P^T  -> D[d][q], col = q  (rescale per-lane).
__global__ __launch_bounds__(256) void attn_kernel(
    const bf16* __restrict__ Qh, const bf16* __restrict__ Kh, const bf16* __restrict__ Vt,
    const float* __restrict__ mask, bf16* __restrict__ ctx)
{
    // double-buffered K and V tiles: 64 rows x 64 cols bf16, XOR-swizzled (byte ^= (row&7)<<4)
    __shared__ bf16 Kl[2][4096];
    __shared__ bf16 Vl[2][4096];

    const int t = threadIdx.x;
    const int lane = t & 63, w = t >> 6;
    const int lq = lane & 31;          // q-col / A-row index
    const int hi = lane >> 5;
    const int bh = blockIdx.y;
    const int b = bh / NHEAD, h = bh % NHEAD;
    const size_t base = (size_t)bh * SEQ * HDIM;
    const int qw = blockIdx.x * 128 + w * 32;    // this wave's q base

    // Q fragments (pre-scaled): B-frag lane holds Q[qw+lq][dc*16 + hi*8 + j]
    bf16x8 qf[4];
    {
        const bf16* qp = Qh + base + (size_t)(qw + lq) * HDIM + hi * 8;
#pragma unroll
        for (int dc = 0; dc < 4; dc++)
            qf[dc] = *reinterpret_cast<const bf16x8*>(qp + dc * 16);
    }
    const float* maskb = mask + b * SEQ;

    // staging source (pre-swizzled global address so linear global_load_lds dest == swizzled LDS)
    const int r8 = lane >> 3;          // 0..7
    const int c8 = lane & 7;
    const bf16* kstage = Kh + base + (size_t)(16 * w + r8) * HDIM + (c8 ^ r8) * 8;
    const bf16* vstage = Vt + base + (size_t)(16 * w + r8) * SEQ  + (c8 ^ r8) * 8;

#define STAGE(BUFI, KT)                                                                              \
    {                                                                                                \
        const bf16* ks_ = kstage + (size_t)(KT) * 64 * HDIM;                                         \
        const bf16* vs_ = vstage + (size_t)(KT) * 64;                                                \
        _Pragma("unroll")                                                                            \
        for (int i_ = 0; i_ < 2; i_++) {                                                             \
            __builtin_amdgcn_global_load_lds(                                                        \
                (const __attribute__((address_space(1))) void*)(ks_ + i_ * 8 * HDIM),                \
                (__attribute__((address_space(3))) void*)(&Kl[BUFI][w * 1024 + i_ * 512]), 16, 0, 0);\
            __builtin_amdgcn_global_load_lds(                                                        \
                (const __attribute__((address_space(1))) void*)(vs_ + (size_t)i_ * 8 * SEQ),         \
                (__attribute__((address_space(3))) void*)(&Vl[BUFI][w * 1024 + i_ * 512]), 16, 0, 0);\
        }                                                                                            \
    }

    float m_r = -3e38f, l_r = 0.f;
    f32x16 o0 = {}, o1 = {};
    const int swr = (lq & 7) << 4;

    int buf = 0;
    STAGE(0, 0);

    const int NT = SEQ / 64;
    for (int kt = 0; kt < NT; kt++) {
        __syncthreads();                       // staged tile ready; prev reads done
        if (kt + 1 < NT) STAGE(buf ^ 1, kt + 1);

        // ---- QK^T: S[k][q], two 32-k subtiles ----
        const char* kb = (const char*)(&Kl[buf][0]);
        f32x16 s0 = {}, s1 = {};
#pragma unroll
        for (int dc = 0; dc < 4; dc++) {
            int col = (dc * 32 + hi * 16) ^ swr;
            bf16x8 k0 = *(const bf16x8*)(kb + lq * 128 + col);
            bf16x8 k1 = *(const bf16x8*)(kb + (32 + lq) * 128 + col);
            s0 = __builtin_amdgcn_mfma_f32_32x32x16_bf16(k0, qf[dc], s0, 0, 0, 0);
            s1 = __builtin_amdgcn_mfma_f32_32x32x16_bf16(k1, qf[dc], s1, 0, 0, 0);
        }

        // ---- softmax (exp2 domain, per-lane state) ----
        const float* mrow = maskb + kt * 64 + hi * 4;
        float tmax = -3e38f;
#pragma unroll
        for (int ks = 0; ks < 2; ks++) {
            f32x16& sc = ks ? s1 : s0;
#pragma unroll
            for (int g4 = 0; g4 < 4; g4++) {
                f32x4 mk = *(const f32x4*)(mrow + ks * 32 + g4 * 8);
#pragma unroll
                for (int j = 0; j < 4; j++) {
                    float v = sc[g4 * 4 + j] + mk[j] * LOG2E;
                    sc[g4 * 4 + j] = v;
                    tmax = fmaxf(tmax, v);
                }
            }
        }
        tmax = fmaxf(tmax, __shfl_xor(tmax, 32));

        if (__any(tmax > m_r + 8.f)) {         // defer-max (T13)
            float mnew = fmaxf(m_r, tmax);
            float alpha = exp2f(m_r - mnew);
            m_r = mnew;
            l_r *= alpha;
#pragma unroll
            for (int i = 0; i < 16; i++) { o0[i] *= alpha; o1[i] *= alpha; }
        }

        float tsum = 0.f;
#pragma unroll
        for (int ks = 0; ks < 2; ks++) {
            f32x16& sc = ks ? s1 : s0;
#pragma unroll
            for (int i = 0; i < 16; i++) {
                float pv = exp2f(sc[i] - m_r);
                sc[i] = pv;
                tsum += pv;
            }
        }
        tsum += __shfl_xor(tsum, 32);
        l_r += tsum;

        // ---- P (f32, D-layout) -> bf16 B-frags via cvt_pk + permlane32_swap ----
        bf16x8 pa[4];
#pragma unroll
        for (int ks = 0; ks < 2; ks++) {
            f32x16& sc = ks ? s1 : s0;
            unsigned u0 = pkbf(sc[0], sc[1]),   u1 = pkbf(sc[2], sc[3]);
            unsigned u2 = pkbf(sc[4], sc[5]),   u3 = pkbf(sc[6], sc[7]);
            unsigned u4 = pkbf(sc[8], sc[9]),   u5 = pkbf(sc[10], sc[11]);
            unsigned u6 = pkbf(sc[12], sc[13]), u7 = pkbf(sc[14], sc[15]);
            asm("v_permlane32_swap_b32 %0, %1" : "+v"(u0), "+v"(u2));
            asm("v_permlane32_swap_b32 %0, %1" : "+v"(u1), "+v"(u3));
            asm("v_permlane32_swap_b32 %0, %1" : "+v"(u4), "+v"(u6));
            asm("v_permlane32_swap_b32 %0, %1" : "+v"(u5), "+v"(u7));
            union { unsigned u[4]; bf16x8 v; } f0, f1;
            f0.u[0] = u0; f0.u[1] = u1; f0.u[2] = u2; f0.u[3] = u3;
            f1.u[0] = u4; f1.u[1] = u5; f1.u[2] = u6; f1.u[3] = u7;
            pa[ks * 2]     = f0.v;
            pa[ks * 2 + 1] = f1.v;
        }

        // ---- PV: O^T[d][q] += V^T * P^T ----
        const char* vb = (const char*)(&Vl[buf][0]);
#pragma unroll
        for (int kc = 0; kc < 4; kc++) {
            int col = (kc * 32 + hi * 16) ^ swr;
            bf16x8 v0 = *(const bf16x8*)(vb + lq * 128 + col);
            bf16x8 v1 = *(const bf16x8*)(vb + (32 + lq) * 128 + col);
            o0 = __builtin_amdgcn_mfma_f32_32x32x16_bf16(v0, pa[kc], o0, 0, 0, 0);
            o1 = __builtin_amdgcn_mfma_f32_32x32x16_bf16(v1, pa[kc], o1, 0, 0, 0);
        }
        buf ^= 1;
    }

    // ---- epilogue: O/l -> LDS (coalesce) -> global ----
    float invl = 1.f / l_r;
    __syncthreads();                            // all waves done reading K/V LDS
    bf16* oreg = ((bf16*)Kl) + w * 2048;        // per-wave 32x64 bf16 region (swizzled)
#pragma unroll
    for (int dn = 0; dn < 2; dn++) {
        f32x16& oo = dn ? o1 : o0;
#pragma unroll
        for (int g4 = 0; g4 < 4; g4++) {
            bf16x4 pk4;
#pragma unroll
            for (int j = 0; j < 4; j++) pk4[j] = (bf16)(oo[g4 * 4 + j] * invl);
            int colb = (dn * 64 + g4 * 16 + hi * 8) ^ swr;
            *(bf16x4*)((char*)oreg + lq * 128 + colb) = pk4;
        }
    }
    // same wave reads back its own region (lgkmcnt handled by compiler)
#pragma unroll
    for (int c = 0; c < 4; c++) {
        int row = c * 8 + r8;
        int colb = (c8 * 16) ^ (r8 << 4);
        bf16x8 val = *(const bf16x8*)((const char*)oreg + row * 128 + colb);
        *(bf16x8*)(ctx + (size_t)(b * SEQ + qw + row) * HID + h * 64 + c8 * 8) = val;
    }
#undef STAGE
}

// ---------------- output projection + bias + residual ----------------
__global__ __launch_bounds__(256) void oproj_gemm(
    const bf16* __restrict__ Cb, const bf16* __restrict__ Wo, const float* __restrict__ bo,
    const float* __restrict__ hidden, float* __restrict__ y)
{
    int lane = threadIdx.x & 63;
    int wid  = threadIdx.x >> 6;
    int wm = wid >> 1, wn = wid & 1;
    int g = lane >> 4, c = lane & 15;
    int m0 = blockIdx.y * 128 + wm * 64;
    int n0 = blockIdx.x * 128 + wn * 64;

    f32x4 acc[4][4] = {};
    const bf16* Aptr = Cb + (size_t)(m0 + c) * HID + g * 8;
    const bf16* Bptr = Wo + (size_t)(n0 + c) * HID + g * 8;

    for (int k0 = 0; k0 < HID; k0 += 32) {
        bf16x8 a[4], b[4];
#pragma unroll
        for (int i = 0; i < 4; i++) {
            a[i] = *reinterpret_cast<const bf16x8*>(Aptr + (size_t)i * 16 * HID + k0);
            b[i] = *reinterpret_cast<const bf16x8*>(Bptr + (size_t)i * 16 * HID + k0);
        }
#pragma unroll
        for (int mi = 0; mi < 4; mi++)
#pragma unroll
            for (int ni = 0; ni < 4; ni++)
                acc[mi][ni] = __builtin_amdgcn_mfma_f32_16x16x32_bf16(a[mi], b[ni], acc[mi][ni], 0, 0, 0);
    }

#pragma unroll
    for (int ni = 0; ni < 4; ni++) {
        int n = n0 + ni * 16 + c;
        float bval = bo[n];
#pragma unroll
        for (int mi = 0; mi < 4; mi++) {
#pragma unroll
            for (int j = 0; j < 4; j++) {
                int m = m0 + mi * 16 + g * 4 + j;
                size_t idx = (size_t)m * HID + n;
                y[idx] = acc[mi][ni][j] + bval + hidden[idx];
            }
        }
    }
}

// ---------------- LayerNorm ----------------
__global__ __launch_bounds__(256) void ln_kernel(
    const float* __restrict__ y, const float* __restrict__ gam,
    const float* __restrict__ bet, float* __restrict__ out)
{
    int row = blockIdx.x * 4 + (threadIdx.x >> 6);
    int lane = threadIdx.x & 63;
    const float* yr = y + (size_t)row * HID;

    float4 v[3];
#pragma unroll
    for (int i = 0; i < 3; i++)
        v[i] = reinterpret_cast<const float4*>(yr)[lane + i * 64];

    float s = 0.f;
#pragma unroll
    for (int i = 0; i < 3; i++) s += v[i].x + v[i].y + v[i].z + v[i].w;
#pragma unroll
    for (int msk = 1; msk < 64; msk <<= 1) s += __shfl_xor(s, msk, 64);
    float mean = s * (1.f / 768.f);

    float q = 0.f;
#pragma unroll
    for (int i = 0; i < 3; i++) {
        float dx = v[i].x - mean, dy = v[i].y - mean, dz = v[i].z - mean, dw = v[i].w - mean;
        q += dx * dx + dy * dy + dz * dz + dw * dw;
    }
#pragma unroll
    for (int msk = 1; msk < 64; msk <<= 1) q += __shfl_xor(q, msk, 64);
    float rstd = rsqrtf(q * (1.f / 768.f) + 1e-12f);

    float* outr = out + (size_t)row * HID;
#pragma unroll
    for (int i = 0; i < 3; i++) {
        float4 gg = reinterpret_cast<const float4*>(gam)[lane + i * 64];
        float4 bb = reinterpret_cast<const float4*>(bet)[lane + i * 64];
        float4 o;
        o.x = (v[i].x - mean) * rstd * gg.x + bb.x;
        o.y = (v[i].y - mean) * rstd * gg.y + bb.y;
        o.z = (v[i].z - mean) * rstd * gg.z + bb.z;
        o.w = (v[i].w - mean) * rstd * gg.w + bb.w;
        reinterpret_cast<float4*>(outr)[lane + i * 64] = o;
    }
}

extern "C" void kernel_launch(void* const* d_in, const int* in_sizes, int n_in,
                              void* d_out, int out_size, void* d_ws, size_t ws_size,
                              hipStream_t stream) {
    const float* hidden = (const float*)d_in[0];
    const float* mask   = (const float*)d_in[1];
    const float* q_w = (const float*)d_in[2];
    const float* q_b = (const float*)d_in[3];
    const float* k_w = (const float*)d_in[4];
    const float* k_b = (const float*)d_in[5];
    const float* v_w = (const float*)d_in[6];
    const float* v_b = (const float*)d_in[7];
    const float* o_w = (const float*)d_in[8];
    const float* o_b = (const float*)d_in[9];
    const float* ln_g = (const float*)d_in[10];
    const float* ln_b = (const float*)d_in[11];
    float* out = (float*)d_out;

    const size_t SZ_X = (size_t)MTOT * HID;
    const size_t SZ_W = (size_t)HID * HID;

    char* ws = (char*)d_ws;
    size_t XB_OFF = 0;
    size_t W_OFF  = XB_OFF + SZ_X * 2;
    size_t QH_OFF = W_OFF + 4 * SZ_W * 2;
    size_t KH_OFF = QH_OFF + SZ_X * 2;
    size_t VT_OFF = KH_OFF + SZ_X * 2;

    bf16* Xb  = (bf16*)(ws + XB_OFF);
    bf16* Wqb = (bf16*)(ws + W_OFF);
    bf16* Wkb = Wqb + SZ_W;
    bf16* Wvb = Wkb + SZ_W;
    bf16* Wob = Wvb + SZ_W;
    bf16* Qh  = (bf16*)(ws + QH_OFF);
    bf16* Kh  = (bf16*)(ws + KH_OFF);
    bf16* Vt  = (bf16*)(ws + VT_OFF);
    bf16* ctx = (bf16*)(ws + XB_OFF);
    float* y  = (float*)(ws + QH_OFF);

    cvt_kernel<<<dim3((SZ_X / 4 + 255) / 256), 256, 0, stream>>>(hidden, Xb, SZ_X / 4);
    cvt_kernel<<<dim3((SZ_W / 4 + 255) / 256), 256, 0, stream>>>(q_w, Wqb, SZ_W / 4);
    cvt_kernel<<<dim3((SZ_W / 4 + 255) / 256), 256, 0, stream>>>(k_w, Wkb, SZ_W / 4);
    cvt_kernel<<<dim3((SZ_W / 4 + 255) / 256), 256, 0, stream>>>(v_w, Wvb, SZ_W / 4);
    cvt_kernel<<<dim3((SZ_W / 4 + 255) / 256), 256, 0, stream>>>(o_w, Wob, SZ_W / 4);

    qkv_gemm<<<dim3(HID / 128, MTOT / 128, 3), 256, 0, stream>>>(
        Xb, Wqb, Wkb, Wvb, q_b, k_b, v_b, Qh, Kh, Vt);

    attn_kernel<<<dim3(SEQ / 128, NB * NHEAD), 256, 0, stream>>>(Qh, Kh, Vt, mask, ctx);

    oproj_gemm<<<dim3(HID / 128, MTOT / 128), 256, 0, stream>>>(ctx, Wob, o_b, hidden, y);

    ln_kernel<<<dim3(MTOT / 4), 256, 0, stream>>>(y, ln_g, ln_b, out);
}